// Round 15
// baseline (21.119 us; speedup 1.0000x reference)
//
#include <hip/hip_runtime.h>

#define NH 64
#define LFULL 2048
#define MH 1024
#define PI_F 3.14159265358979323846f
#define ANG_HALF 1.5339807878856412e-3f   // pi/2048
#define ANG_3A   3.0679615757712823e-3f   // pi/1024
#define ANG_FFT  6.1359231515425647e-3f   // pi/512

typedef __attribute__((ext_vector_type(2))) float f32x2;
typedef __attribute__((ext_vector_type(4))) float f32x4;

#define SV2(v, i, j) __builtin_shufflevector((v), (v), (i), (j))

// One pole at z=iy for one packed freq-pair, accumulator set G (token-pasted).
// SEL = "0"/"1" selects the coefficient half via op_sel broadcast.
// term = [P1 + i*P0*y]/[(m2-y^2)+i*na2*y]; s1=ΣP1U, s2=ΣP1V, s3=ΣP0U, s4=ΣP0V.
#define ONE_POLE_G(SEL, G, YP, NYY2) do {                                            \
    f32x2 dr, di;                                                                    \
    asm("v_pk_add_f32 %0, %1, %2 op_sel:[" SEL ",0] op_sel_hi:[" SEL ",1]"           \
        : "=v"(dr) : "v"(pm2), "v"(NYY2));                                           \
    asm("v_pk_mul_f32 %0, %1, %2 op_sel:[" SEL ",0] op_sel_hi:[" SEL ",1]"           \
        : "=v"(di) : "v"(pna), "v"(YP));                                             \
    const f32x2 den = dr*dr + di*di;                                                 \
    const float pprod = den.x * den.y;                                               \
    const float ipp = __builtin_amdgcn_rcpf(pprod);                                  \
    f32x2 t;  t.x = ipp * den.y;  t.y = ipp * den.x;                                 \
    const f32x2 U = dr * t;                                                          \
    const f32x2 V = di * t;                                                          \
    asm("v_pk_fma_f32 %0, %1, %2, %0 op_sel:[" SEL ",0,0] op_sel_hi:[" SEL ",1,1]"   \
        : "+v"(s1_00##G) : "v"(pa00), "v"(U));                                       \
    asm("v_pk_fma_f32 %0, %1, %2, %0 op_sel:[" SEL ",0,0] op_sel_hi:[" SEL ",1,1]"   \
        : "+v"(s2_00##G) : "v"(pa00), "v"(V));                                       \
    asm("v_pk_fma_f32 %0, %1, %2, %0 op_sel:[" SEL ",0,0] op_sel_hi:[" SEL ",1,1]"   \
        : "+v"(s3_00##G) : "v"(pb00), "v"(U));                                       \
    asm("v_pk_fma_f32 %0, %1, %2, %0 op_sel:[" SEL ",0,0] op_sel_hi:[" SEL ",1,1]"   \
        : "+v"(s4_00##G) : "v"(pb00), "v"(V));                                       \
    asm("v_pk_fma_f32 %0, %1, %2, %0 op_sel:[" SEL ",0,0] op_sel_hi:[" SEL ",1,1]"   \
        : "+v"(s1_01##G) : "v"(pa01), "v"(U));                                       \
    asm("v_pk_fma_f32 %0, %1, %2, %0 op_sel:[" SEL ",0,0] op_sel_hi:[" SEL ",1,1]"   \
        : "+v"(s2_01##G) : "v"(pa01), "v"(V));                                       \
    asm("v_pk_fma_f32 %0, %1, %2, %0 op_sel:[" SEL ",0,0] op_sel_hi:[" SEL ",1,1]"   \
        : "+v"(s3_01##G) : "v"(pb01), "v"(U));                                       \
    asm("v_pk_fma_f32 %0, %1, %2, %0 op_sel:[" SEL ",0,0] op_sel_hi:[" SEL ",1,1]"   \
        : "+v"(s4_01##G) : "v"(pb01), "v"(V));                                       \
    asm("v_pk_fma_f32 %0, %1, %2, %0 op_sel:[" SEL ",0,0] op_sel_hi:[" SEL ",1,1]"   \
        : "+v"(s1_10##G) : "v"(pa10), "v"(U));                                       \
    asm("v_pk_fma_f32 %0, %1, %2, %0 op_sel:[" SEL ",0,0] op_sel_hi:[" SEL ",1,1]"   \
        : "+v"(s2_10##G) : "v"(pa10), "v"(V));                                       \
    asm("v_pk_fma_f32 %0, %1, %2, %0 op_sel:[" SEL ",0,0] op_sel_hi:[" SEL ",1,1]"   \
        : "+v"(s3_10##G) : "v"(pb10), "v"(U));                                       \
    asm("v_pk_fma_f32 %0, %1, %2, %0 op_sel:[" SEL ",0,0] op_sel_hi:[" SEL ",1,1]"   \
        : "+v"(s4_10##G) : "v"(pb10), "v"(V));                                       \
    asm("v_pk_fma_f32 %0, %1, %2, %0 op_sel:[" SEL ",0,0] op_sel_hi:[" SEL ",1,1]"   \
        : "+v"(s1_11##G) : "v"(pa11), "v"(U));                                       \
    asm("v_pk_fma_f32 %0, %1, %2, %0 op_sel:[" SEL ",0,0] op_sel_hi:[" SEL ",1,1]"   \
        : "+v"(s2_11##G) : "v"(pa11), "v"(V));                                       \
    asm("v_pk_fma_f32 %0, %1, %2, %0 op_sel:[" SEL ",0,0] op_sel_hi:[" SEL ",1,1]"   \
        : "+v"(s3_11##G) : "v"(pb11), "v"(U));                                       \
    asm("v_pk_fma_f32 %0, %1, %2, %0 op_sel:[" SEL ",0,0] op_sel_hi:[" SEL ",1,1]"   \
        : "+v"(s4_11##G) : "v"(pb11), "v"(V));                                       \
} while (0)

// Woodbury + spectral twist for one packed freq-pair, accumulator set G.
#define FINISH_G(G, YP, L0, L1) do {                                                 \
    const f32x2 r00r = (YP)*s4_00##G + s1_00##G;                                     \
    const f32x2 r00i = (YP)*s3_00##G - s2_00##G;                                     \
    const f32x2 r01r = (YP)*s4_01##G + s1_01##G;                                     \
    const f32x2 r01i = (YP)*s3_01##G - s2_01##G;                                     \
    const f32x2 r10r = (YP)*s4_10##G + s1_10##G;                                     \
    const f32x2 r10i = (YP)*s3_10##G - s2_10##G;                                     \
    const f32x2 r11r = (YP)*s4_11##G + s1_11##G;                                     \
    const f32x2 r11i = (YP)*s3_11##G - s2_11##G;                                     \
    const f32x2 nr = r01r*r10r - r01i*r10i;                                          \
    const f32x2 ni = r01r*r10i + r01i*r10r;                                          \
    const f32x2 dw = 1.f + r11r;                                                     \
    const f32x2 dv = r11i;                                                           \
    const f32x2 d2 = dw*dw + dv*dv;                                                  \
    f32x2 id2;                                                                       \
    id2.x = __builtin_amdgcn_rcpf(d2.x);                                             \
    id2.y = __builtin_amdgcn_rcpf(d2.y);                                             \
    const f32x2 cr = (nr*dw + ni*dv)*id2;                                            \
    const f32x2 ci = (ni*dw - nr*dv)*id2;                                            \
    const f32x2 k0r = r00r - cr;                                                     \
    const f32x2 k0i = r00i - ci;                                                     \
    const f32x2 hy = 0.5f*(YP);                                                      \
    Kf[(L0)] = make_float2(k0r.x - k0i.x*hy.x, k0i.x + k0r.x*hy.x);                  \
    Kf[(L1)] = make_float2(k0r.y - k0i.y*hy.y, k0i.y + k0r.y*hy.y);                  \
} while (0)

__global__ __launch_bounds__(512) void hippo_ssk(
    const float* __restrict__ w_ri,
    const float* __restrict__ P_ri,
    const float* __restrict__ B_ri,
    const float* __restrict__ C_ri,
    const float* __restrict__ log_dt,
    float* __restrict__ out)
{
    __shared__ __attribute__((aligned(16))) float coeff[10][NH];
    __shared__ float2 Kf[MH + 1];
    __shared__ float2 bufA[MH];
    __shared__ float2 bufB[MH];

    const int h    = blockIdx.x;
    const int tid  = threadIdx.x;
    const int c    = tid & 255;        // merged-stage butterfly id
    const int eps  = tid >> 8;         // wave-uniform

    // ---------------- Wave 0: issue stage-1 global loads EARLY ----------------
    float2 w_, P_, B_, C_;  float dtv = 0.f;
    if (tid < NH) {
        dtv = log_dt[h];
        w_ = ((const float2*)w_ri)[h*NH + tid];
        P_ = ((const float2*)P_ri)[h*NH + tid];
        B_ = ((const float2*)B_ri)[h*NH + tid];
        C_ = ((const float2*)C_ri)[h*NH + tid];
    }

    // ---------------- Hoisted trig (overlaps wave-0 load latency) ----------------
    // Stage-2 freqs: thread t<256 handles (t, t+512) and (t+256, t+768)
    f32x2 ypA, nyy2A, ypB, nyy2B;
    {
        float sh0, ch0, sh1, ch1, sh2, ch2, sh3, ch3;
        __sincosf(ANG_HALF * (float)c,         &sh0, &ch0);
        __sincosf(ANG_HALF * (float)(c + 512), &sh1, &ch1);
        __sincosf(ANG_HALF * (float)(c + 256), &sh2, &ch2);
        __sincosf(ANG_HALF * (float)(c + 768), &sh3, &ch3);
        const float y0 = 2.f * sh0 * __builtin_amdgcn_rcpf(ch0);
        const float y1 = 2.f * sh1 * __builtin_amdgcn_rcpf(ch1);
        const float y2 = 2.f * sh2 * __builtin_amdgcn_rcpf(ch2);
        const float y3 = 2.f * sh3 * __builtin_amdgcn_rcpf(ch3);
        ypA.x = y0;  ypA.y = y1;  nyy2A.x = -y0*y0;  nyy2A.y = -y1*y1;
        ypB.x = y2;  ypB.y = y3;  nyy2B.x = -y2*y2;  nyy2B.y = -y3*y3;
    }
    // 3a / stage-0 twiddle (all 512 threads)
    float sa, ca;
    __sincosf(ANG_3A * (float)tid, &sa, &ca);
    const float cw0 = ca*ca - sa*sa;     // e^{+i*pi*tid/512}
    const float sw0 = 2.f*ca*sa;
    // Merged-stage twiddles w1 = e^{+i*pi*(c & ~(m-1))/512}, m = 2,8,32,128
    float w1c[4], w1s[4];
    #pragma unroll
    for (int mi = 0; mi < 4; ++mi) {
        const int m = 2 << (2*mi);
        __sincosf(ANG_FFT * (float)(c & ~(m-1)), &w1s[mi], &w1c[mi]);
    }

    // ---------------- Stage 1: per-pole quadratic coefficients (wave 0) ----------------
    if (tid < NH) {
        const float dt = __expf(dtv);
        const float a = w_.x * dt, b = w_.y * dt;
        const float v00r = (B_.x*C_.x - B_.y*C_.y) * dt;
        const float v00i = (B_.x*C_.y + B_.y*C_.x) * dt;
        const float v01r = (B_.x*P_.x + B_.y*P_.y) * dt;   // B*conj(P)
        const float v01i = (B_.y*P_.x - B_.x*P_.y) * dt;
        const float v10r = (P_.x*C_.x - P_.y*C_.y) * dt;   // P*C
        const float v10i = (P_.x*C_.y + P_.y*C_.x) * dt;
        const float v11  = (P_.x*P_.x + P_.y*P_.y) * dt;   // |P|^2 (real)
        coeff[0][tid] = -2.f*a;
        coeff[1][tid] = fmaf(a, a, b*b);
        coeff[2][tid] = -2.f*fmaf(v00r, a, v00i*b);
        coeff[3][tid] = 2.f*v00r;
        coeff[4][tid] = -2.f*fmaf(v01r, a, v01i*b);
        coeff[5][tid] = 2.f*v01r;
        coeff[6][tid] = -2.f*fmaf(v10r, a, v10i*b);
        coeff[7][tid] = 2.f*v10r;
        coeff[8][tid] = -2.f*v11*a;
        coeff[9][tid] = 2.f*v11;
        float s = v00r;   // Nyquist bin: Re(sum v00)
        #pragma unroll
        for (int off = 32; off > 0; off >>= 1) s += __shfl_down(s, off, 64);
        if (tid == 0) Kf[MH] = make_float2(s, 0.f);
    }
    __syncthreads();

    // ---------------- Stage 2: Cauchy — 256 threads × 4 freqs (2 packed pairs) ----------------
    if (tid < 256) {
        f32x2 s1_00A={0,0}, s2_00A={0,0}, s3_00A={0,0}, s4_00A={0,0};
        f32x2 s1_01A={0,0}, s2_01A={0,0}, s3_01A={0,0}, s4_01A={0,0};
        f32x2 s1_10A={0,0}, s2_10A={0,0}, s3_10A={0,0}, s4_10A={0,0};
        f32x2 s1_11A={0,0}, s2_11A={0,0}, s3_11A={0,0}, s4_11A={0,0};
        f32x2 s1_00B={0,0}, s2_00B={0,0}, s3_00B={0,0}, s4_00B={0,0};
        f32x2 s1_01B={0,0}, s2_01B={0,0}, s3_01B={0,0}, s4_01B={0,0};
        f32x2 s1_10B={0,0}, s2_10B={0,0}, s3_10B={0,0}, s4_10B={0,0};
        f32x2 s1_11B={0,0}, s2_11B={0,0}, s3_11B={0,0}, s4_11B={0,0};
        for (int n = 0; n < NH; n += 4) {
            const f32x4 q0 = *reinterpret_cast<const f32x4*>(&coeff[0][n]);
            const f32x4 q1 = *reinterpret_cast<const f32x4*>(&coeff[1][n]);
            const f32x4 q2 = *reinterpret_cast<const f32x4*>(&coeff[2][n]);
            const f32x4 q3 = *reinterpret_cast<const f32x4*>(&coeff[3][n]);
            const f32x4 q4 = *reinterpret_cast<const f32x4*>(&coeff[4][n]);
            const f32x4 q5 = *reinterpret_cast<const f32x4*>(&coeff[5][n]);
            const f32x4 q6 = *reinterpret_cast<const f32x4*>(&coeff[6][n]);
            const f32x4 q7 = *reinterpret_cast<const f32x4*>(&coeff[7][n]);
            const f32x4 q8 = *reinterpret_cast<const f32x4*>(&coeff[8][n]);
            const f32x4 q9 = *reinterpret_cast<const f32x4*>(&coeff[9][n]);
            {   // poles n, n+1 (low pairs)
                const f32x2 pna = SV2(q0,0,1), pm2 = SV2(q1,0,1);
                const f32x2 pa00 = SV2(q2,0,1), pb00 = SV2(q3,0,1);
                const f32x2 pa01 = SV2(q4,0,1), pb01 = SV2(q5,0,1);
                const f32x2 pa10 = SV2(q6,0,1), pb10 = SV2(q7,0,1);
                const f32x2 pa11 = SV2(q8,0,1), pb11 = SV2(q9,0,1);
                ONE_POLE_G("0", A, ypA, nyy2A);
                ONE_POLE_G("0", B, ypB, nyy2B);
                ONE_POLE_G("1", A, ypA, nyy2A);
                ONE_POLE_G("1", B, ypB, nyy2B);
            }
            {   // poles n+2, n+3 (high pairs)
                const f32x2 pna = SV2(q0,2,3), pm2 = SV2(q1,2,3);
                const f32x2 pa00 = SV2(q2,2,3), pb00 = SV2(q3,2,3);
                const f32x2 pa01 = SV2(q4,2,3), pb01 = SV2(q5,2,3);
                const f32x2 pa10 = SV2(q6,2,3), pb10 = SV2(q7,2,3);
                const f32x2 pa11 = SV2(q8,2,3), pb11 = SV2(q9,2,3);
                ONE_POLE_G("0", A, ypA, nyy2A);
                ONE_POLE_G("0", B, ypB, nyy2B);
                ONE_POLE_G("1", A, ypA, nyy2A);
                ONE_POLE_G("1", B, ypB, nyy2B);
            }
        }
        FINISH_G(A, ypA, c,       c + 512);
        FINISH_G(B, ypB, c + 256, c + 768);
    }
    __syncthreads();

    // ---------------- Stage 3: fused 3a + FFT stage 0 (m=1), b128 write ----------------
    {
        float2 Xk = Kf[tid];
        if (tid == 0) Xk.y = 0.f;
        float2 Xc = Kf[MH - tid];  Xc.y = -Xc.y;
        const float Er0 = 0.5f*(Xk.x + Xc.x), Ei0 = 0.5f*(Xk.y + Xc.y);
        const float Tr0 = 0.5f*(Xk.x - Xc.x), Ti0 = 0.5f*(Xk.y - Xc.y);
        const float2 Z0 = make_float2(Er0 - (ca*Ti0 + sa*Tr0), Ei0 + (ca*Tr0 - sa*Ti0));
        const float2 Xk1 = Kf[tid + 512];
        float2 Xc1 = Kf[512 - tid];  Xc1.y = -Xc1.y;
        const float Er1 = 0.5f*(Xk1.x + Xc1.x), Ei1 = 0.5f*(Xk1.y + Xc1.y);
        const float Tr1 = 0.5f*(Xk1.x - Xc1.x), Ti1 = 0.5f*(Xk1.y - Xc1.y);
        const float Or1 = -sa*Tr1 - ca*Ti1;      // twiddle i*(ca,sa) = (-sa, ca)
        const float Oi1 = -sa*Ti1 + ca*Tr1;
        const float2 Z1 = make_float2(Er1 - Oi1, Ei1 + Or1);
        const float drr = Z0.x - Z1.x, dii = Z0.y - Z1.y;
        float4 outv;
        outv.x = Z0.x + Z1.x;
        outv.y = Z0.y + Z1.y;
        outv.z = cw0*drr - sw0*dii;
        outv.w = cw0*dii + sw0*drr;
        *reinterpret_cast<float4*>(&bufA[2*tid]) = outv;
    }
    __syncthreads();

    // ---------------- Merged FFT stages: (m,2m) for m = 2, 8, 32, 128 ----------------
    float2* Xb = bufA;
    float2* Yb = bufB;
    #pragma unroll
    for (int mi = 0; mi < 4; ++mi) {
        const int m   = 2 << (2*mi);
        const int jm1 = c & ~(m - 1);
        const int r   = c & (m - 1);
        const float c1v = w1c[mi], s1 = w1s[mi];
        const float2 x0 = Xb[c];
        const float2 x1 = Xb[c + 256];
        const float2 x2 = Xb[c + 512];
        const float2 x3 = Xb[c + 768];
        const float2 s02 = make_float2(x0.x + x2.x, x0.y + x2.y);
        const float2 d02 = make_float2(x0.x - x2.x, x0.y - x2.y);
        const float2 s13 = make_float2(x1.x + x3.x, x1.y + x3.y);
        const float2 d13 = make_float2(x1.x - x3.x, x1.y - x3.y);
        const float2 wd02 = make_float2(c1v*d02.x - s1*d02.y, c1v*d02.y + s1*d02.x);
        const float2 wd13 = make_float2(-s1*d13.x - c1v*d13.y, c1v*d13.x - s1*d13.y);
        const float2 Yu = eps ? wd02 : s02;
        const float2 Yv = eps ? wd13 : s13;
        const float Wc = c1v*c1v - s1*s1;     // W = w1^2
        const float Ws = 2.f*c1v*s1;
        const float2 Zp = make_float2(Yu.x + Yv.x, Yu.y + Yv.y);
        const float2 Zd = make_float2(Yu.x - Yv.x, Yu.y - Yv.y);
        const int p = 4*jm1 + (eps ? m : 0) + r;
        Yb[p]       = Zp;
        Yb[p + 2*m] = make_float2(Wc*Zd.x - Ws*Zd.y, Wc*Zd.y + Ws*Zd.x);
        __syncthreads();
        float2* t = Xb; Xb = Yb; Yb = t;
    }

    // ---------------- Final stage m=512 (twiddle-free) fused with store ----------------
    {
        const float sc = 1.0f/1024.0f;
        float2* op2 = (float2*)(out + (size_t)h * LFULL);
        const float2 a0 = Xb[tid];
        const float2 a1 = Xb[tid + 512];
        op2[tid]       = make_float2((a0.x + a1.x)*sc, (a0.y + a1.y)*sc);
        op2[tid + 512] = make_float2((a0.x - a1.x)*sc, (a0.y - a1.y)*sc);
    }
}

extern "C" void kernel_launch(void* const* d_in, const int* in_sizes, int n_in,
                              void* d_out, int out_size, void* d_ws, size_t ws_size,
                              hipStream_t stream) {
    const float* w_ri   = (const float*)d_in[0];
    const float* P_ri   = (const float*)d_in[1];
    const float* B_ri   = (const float*)d_in[2];
    const float* C_ri   = (const float*)d_in[3];
    const float* log_dt = (const float*)d_in[4];
    float* out = (float*)d_out;
    const int Hn = in_sizes[4];   // 256 heads
    hippo_ssk<<<dim3(Hn), dim3(512), 0, stream>>>(w_ri, P_ri, B_ri, C_ri, log_dt, out);
}

// Round 16
// 15.628 us; speedup vs baseline: 1.3514x; 1.3514x over previous
//
#include <hip/hip_runtime.h>

#define NH 64
#define LFULL 2048
#define MH 1024
#define PI_F 3.14159265358979323846f
#define ANG_HALF 1.5339807878856412e-3f   // pi/2048
#define ANG_3A   3.0679615757712823e-3f   // pi/1024
#define ANG_FFT  6.1359231515425647e-3f   // pi/512

typedef __attribute__((ext_vector_type(2))) float f32x2;
typedef __attribute__((ext_vector_type(4))) float f32x4;

#define SV2(v, i, j) __builtin_shufflevector((v), (v), (i), (j))

// One pole at z=iy, both freqs packed (validated R13). SEL = "0"/"1" selects the
// coefficient half via op_sel broadcast. term = [P1 + i*P0*y]/[(m2-y^2)+i*na2*y];
// accumulate s1=ΣP1U, s2=ΣP1V, s3=ΣP0U, s4=ΣP0V with U=dr/den, V=di/den.
#define ONE_POLE(SEL, pna, pm2, pa00, pb00, pa01, pb01, pa10, pb10, pa11, pb11) do { \
    f32x2 dr, di;                                                                    \
    asm("v_pk_add_f32 %0, %1, %2 op_sel:[" SEL ",0] op_sel_hi:[" SEL ",1]"           \
        : "=v"(dr) : "v"(pm2), "v"(nyy2));                                           \
    asm("v_pk_mul_f32 %0, %1, %2 op_sel:[" SEL ",0] op_sel_hi:[" SEL ",1]"           \
        : "=v"(di) : "v"(pna), "v"(yp));                                             \
    const f32x2 den = dr*dr + di*di;                                                 \
    const float pprod = den.x * den.y;                                               \
    const float ipp = __builtin_amdgcn_rcpf(pprod);                                  \
    f32x2 t;  t.x = ipp * den.y;  t.y = ipp * den.x;                                 \
    const f32x2 U = dr * t;                                                          \
    const f32x2 V = di * t;                                                          \
    asm("v_pk_fma_f32 %0, %1, %2, %0 op_sel:[" SEL ",0,0] op_sel_hi:[" SEL ",1,1]"   \
        : "+v"(s1_00) : "v"(pa00), "v"(U));                                          \
    asm("v_pk_fma_f32 %0, %1, %2, %0 op_sel:[" SEL ",0,0] op_sel_hi:[" SEL ",1,1]"   \
        : "+v"(s2_00) : "v"(pa00), "v"(V));                                          \
    asm("v_pk_fma_f32 %0, %1, %2, %0 op_sel:[" SEL ",0,0] op_sel_hi:[" SEL ",1,1]"   \
        : "+v"(s3_00) : "v"(pb00), "v"(U));                                          \
    asm("v_pk_fma_f32 %0, %1, %2, %0 op_sel:[" SEL ",0,0] op_sel_hi:[" SEL ",1,1]"   \
        : "+v"(s4_00) : "v"(pb00), "v"(V));                                          \
    asm("v_pk_fma_f32 %0, %1, %2, %0 op_sel:[" SEL ",0,0] op_sel_hi:[" SEL ",1,1]"   \
        : "+v"(s1_01) : "v"(pa01), "v"(U));                                          \
    asm("v_pk_fma_f32 %0, %1, %2, %0 op_sel:[" SEL ",0,0] op_sel_hi:[" SEL ",1,1]"   \
        : "+v"(s2_01) : "v"(pa01), "v"(V));                                          \
    asm("v_pk_fma_f32 %0, %1, %2, %0 op_sel:[" SEL ",0,0] op_sel_hi:[" SEL ",1,1]"   \
        : "+v"(s3_01) : "v"(pb01), "v"(U));                                          \
    asm("v_pk_fma_f32 %0, %1, %2, %0 op_sel:[" SEL ",0,0] op_sel_hi:[" SEL ",1,1]"   \
        : "+v"(s4_01) : "v"(pb01), "v"(V));                                          \
    asm("v_pk_fma_f32 %0, %1, %2, %0 op_sel:[" SEL ",0,0] op_sel_hi:[" SEL ",1,1]"   \
        : "+v"(s1_10) : "v"(pa10), "v"(U));                                          \
    asm("v_pk_fma_f32 %0, %1, %2, %0 op_sel:[" SEL ",0,0] op_sel_hi:[" SEL ",1,1]"   \
        : "+v"(s2_10) : "v"(pa10), "v"(V));                                          \
    asm("v_pk_fma_f32 %0, %1, %2, %0 op_sel:[" SEL ",0,0] op_sel_hi:[" SEL ",1,1]"   \
        : "+v"(s3_10) : "v"(pb10), "v"(U));                                          \
    asm("v_pk_fma_f32 %0, %1, %2, %0 op_sel:[" SEL ",0,0] op_sel_hi:[" SEL ",1,1]"   \
        : "+v"(s4_10) : "v"(pb10), "v"(V));                                          \
    asm("v_pk_fma_f32 %0, %1, %2, %0 op_sel:[" SEL ",0,0] op_sel_hi:[" SEL ",1,1]"   \
        : "+v"(s1_11) : "v"(pa11), "v"(U));                                          \
    asm("v_pk_fma_f32 %0, %1, %2, %0 op_sel:[" SEL ",0,0] op_sel_hi:[" SEL ",1,1]"   \
        : "+v"(s2_11) : "v"(pa11), "v"(V));                                          \
    asm("v_pk_fma_f32 %0, %1, %2, %0 op_sel:[" SEL ",0,0] op_sel_hi:[" SEL ",1,1]"   \
        : "+v"(s3_11) : "v"(pb11), "v"(U));                                          \
    asm("v_pk_fma_f32 %0, %1, %2, %0 op_sel:[" SEL ",0,0] op_sel_hi:[" SEL ",1,1]"   \
        : "+v"(s4_11) : "v"(pb11), "v"(V));                                          \
} while (0)

__global__ __launch_bounds__(512) void hippo_ssk(
    const float* __restrict__ w_ri,
    const float* __restrict__ P_ri,
    const float* __restrict__ B_ri,
    const float* __restrict__ C_ri,
    const float* __restrict__ log_dt,
    float* __restrict__ out)
{
    __shared__ __attribute__((aligned(16))) float coeff[10][NH];
    __shared__ float2 Kf[MH + 1];
    __shared__ float2 bufA[MH];
    __shared__ float2 bufB[MH];

    const int h    = blockIdx.x;
    const int tid  = threadIdx.x;
    const int c    = tid & 255;        // merged-stage butterfly id
    const int eps  = tid >> 8;         // wave-uniform (waves 0-3: 0, waves 4-7: 1)

    // ---------------- Wave 0: issue stage-1 global loads EARLY ----------------
    float2 w_, P_, B_, C_;  float dtv = 0.f;
    if (tid < NH) {
        dtv = log_dt[h];
        w_ = ((const float2*)w_ri)[h*NH + tid];
        P_ = ((const float2*)P_ri)[h*NH + tid];
        B_ = ((const float2*)B_ri)[h*NH + tid];
        C_ = ((const float2*)C_ri)[h*NH + tid];
    }

    // ---------------- All waves: hoisted trig (overlaps wave-0 load latency) ----------------
    // Stage-2 frequencies
    float shA, chA, shB, chB;
    __sincosf(ANG_HALF * (float)tid,         &shA, &chA);
    __sincosf(ANG_HALF * (float)(tid + 512), &shB, &chB);
    const float yA = 2.f * shA * __builtin_amdgcn_rcpf(chA);
    const float yB = 2.f * shB * __builtin_amdgcn_rcpf(chB);
    f32x2 yp;   yp.x = yA;        yp.y = yB;
    f32x2 nyy2; nyy2.x = -yA*yA;  nyy2.y = -yB*yB;
    // 3a / stage-0 twiddle
    float sa, ca;
    __sincosf(ANG_3A * (float)tid, &sa, &ca);
    const float cw0 = ca*ca - sa*sa;     // e^{+i*pi*tid/512}
    const float sw0 = 2.f*ca*sa;
    // Merged-stage twiddles w1 = e^{+i*pi*(c & ~(m-1))/512}, m = 2,8,32,128
    float w1c[4], w1s[4];
    #pragma unroll
    for (int mi = 0; mi < 4; ++mi) {
        const int m = 2 << (2*mi);
        __sincosf(ANG_FFT * (float)(c & ~(m-1)), &w1s[mi], &w1c[mi]);
    }

    // ---------------- Stage 1: per-pole quadratic coefficients (wave 0) ----------------
    if (tid < NH) {
        const float dt = __expf(dtv);
        const float a = w_.x * dt, b = w_.y * dt;
        const float v00r = (B_.x*C_.x - B_.y*C_.y) * dt;
        const float v00i = (B_.x*C_.y + B_.y*C_.x) * dt;
        const float v01r = (B_.x*P_.x + B_.y*P_.y) * dt;   // B*conj(P)
        const float v01i = (B_.y*P_.x - B_.x*P_.y) * dt;
        const float v10r = (P_.x*C_.x - P_.y*C_.y) * dt;   // P*C
        const float v10i = (P_.x*C_.y + P_.y*C_.x) * dt;
        const float v11  = (P_.x*P_.x + P_.y*P_.y) * dt;   // |P|^2 (real)
        coeff[0][tid] = -2.f*a;
        coeff[1][tid] = fmaf(a, a, b*b);
        coeff[2][tid] = -2.f*fmaf(v00r, a, v00i*b);
        coeff[3][tid] = 2.f*v00r;
        coeff[4][tid] = -2.f*fmaf(v01r, a, v01i*b);
        coeff[5][tid] = 2.f*v01r;
        coeff[6][tid] = -2.f*fmaf(v10r, a, v10i*b);
        coeff[7][tid] = 2.f*v10r;
        coeff[8][tid] = -2.f*v11*a;
        coeff[9][tid] = 2.f*v11;
        float s = v00r;   // Nyquist bin: Re(sum v00)
        #pragma unroll
        for (int off = 32; off > 0; off >>= 1) s += __shfl_down(s, off, 64);
        if (tid == 0) Kf[MH] = make_float2(s, 0.f);
    }
    __syncthreads();

    // ---------------- Stage 2: Cauchy, freqs (tid, tid+512) packed (R13-validated) ----------------
    {
        f32x2 s1_00={0,0}, s2_00={0,0}, s3_00={0,0}, s4_00={0,0};
        f32x2 s1_01={0,0}, s2_01={0,0}, s3_01={0,0}, s4_01={0,0};
        f32x2 s1_10={0,0}, s2_10={0,0}, s3_10={0,0}, s4_10={0,0};
        f32x2 s1_11={0,0}, s2_11={0,0}, s3_11={0,0}, s4_11={0,0};
        #pragma unroll 2
        for (int n = 0; n < NH; n += 4) {
            const f32x4 q0 = *reinterpret_cast<const f32x4*>(&coeff[0][n]);
            const f32x4 q1 = *reinterpret_cast<const f32x4*>(&coeff[1][n]);
            const f32x4 q2 = *reinterpret_cast<const f32x4*>(&coeff[2][n]);
            const f32x4 q3 = *reinterpret_cast<const f32x4*>(&coeff[3][n]);
            const f32x4 q4 = *reinterpret_cast<const f32x4*>(&coeff[4][n]);
            const f32x4 q5 = *reinterpret_cast<const f32x4*>(&coeff[5][n]);
            const f32x4 q6 = *reinterpret_cast<const f32x4*>(&coeff[6][n]);
            const f32x4 q7 = *reinterpret_cast<const f32x4*>(&coeff[7][n]);
            const f32x4 q8 = *reinterpret_cast<const f32x4*>(&coeff[8][n]);
            const f32x4 q9 = *reinterpret_cast<const f32x4*>(&coeff[9][n]);
            {
                const f32x2 pna = SV2(q0,0,1), pm2 = SV2(q1,0,1);
                const f32x2 pa00 = SV2(q2,0,1), pb00 = SV2(q3,0,1);
                const f32x2 pa01 = SV2(q4,0,1), pb01 = SV2(q5,0,1);
                const f32x2 pa10 = SV2(q6,0,1), pb10 = SV2(q7,0,1);
                const f32x2 pa11 = SV2(q8,0,1), pb11 = SV2(q9,0,1);
                ONE_POLE("0", pna, pm2, pa00, pb00, pa01, pb01, pa10, pb10, pa11, pb11);
                ONE_POLE("1", pna, pm2, pa00, pb00, pa01, pb01, pa10, pb10, pa11, pb11);
            }
            {
                const f32x2 pna = SV2(q0,2,3), pm2 = SV2(q1,2,3);
                const f32x2 pa00 = SV2(q2,2,3), pb00 = SV2(q3,2,3);
                const f32x2 pa01 = SV2(q4,2,3), pb01 = SV2(q5,2,3);
                const f32x2 pa10 = SV2(q6,2,3), pb10 = SV2(q7,2,3);
                const f32x2 pa11 = SV2(q8,2,3), pb11 = SV2(q9,2,3);
                ONE_POLE("0", pna, pm2, pa00, pb00, pa01, pb01, pa10, pb10, pa11, pb11);
                ONE_POLE("1", pna, pm2, pa00, pb00, pa01, pb01, pa10, pb10, pa11, pb11);
            }
        }
        const f32x2 r00r = yp*s4_00 + s1_00;
        const f32x2 r00i = yp*s3_00 - s2_00;
        const f32x2 r01r = yp*s4_01 + s1_01;
        const f32x2 r01i = yp*s3_01 - s2_01;
        const f32x2 r10r = yp*s4_10 + s1_10;
        const f32x2 r10i = yp*s3_10 - s2_10;
        const f32x2 r11r = yp*s4_11 + s1_11;
        const f32x2 r11i = yp*s3_11 - s2_11;
        const f32x2 nr = r01r*r10r - r01i*r10i;
        const f32x2 ni = r01r*r10i + r01i*r10r;
        const f32x2 dw = 1.f + r11r;
        const f32x2 dv = r11i;
        const f32x2 d2 = dw*dw + dv*dv;
        f32x2 id2;
        id2.x = __builtin_amdgcn_rcpf(d2.x);
        id2.y = __builtin_amdgcn_rcpf(d2.y);
        const f32x2 cr = (nr*dw + ni*dv)*id2;
        const f32x2 ci = (ni*dw - nr*dv)*id2;
        const f32x2 k0r = r00r - cr;
        const f32x2 k0i = r00i - ci;
        const f32x2 hy = 0.5f*yp;
        Kf[tid]       = make_float2(k0r.x - k0i.x*hy.x, k0i.x + k0r.x*hy.x);
        Kf[tid + 512] = make_float2(k0r.y - k0i.y*hy.y, k0i.y + k0r.y*hy.y);
    }
    __syncthreads();

    // ---------------- Stage 3: fused 3a + FFT stage 0 (m=1), b128 write ----------------
    {
        float2 Xk = Kf[tid];
        if (tid == 0) Xk.y = 0.f;
        float2 Xc = Kf[MH - tid];  Xc.y = -Xc.y;
        const float Er0 = 0.5f*(Xk.x + Xc.x), Ei0 = 0.5f*(Xk.y + Xc.y);
        const float Tr0 = 0.5f*(Xk.x - Xc.x), Ti0 = 0.5f*(Xk.y - Xc.y);
        const float2 Z0 = make_float2(Er0 - (ca*Ti0 + sa*Tr0), Ei0 + (ca*Tr0 - sa*Ti0));
        const float2 Xk1 = Kf[tid + 512];
        float2 Xc1 = Kf[512 - tid];  Xc1.y = -Xc1.y;
        const float Er1 = 0.5f*(Xk1.x + Xc1.x), Ei1 = 0.5f*(Xk1.y + Xc1.y);
        const float Tr1 = 0.5f*(Xk1.x - Xc1.x), Ti1 = 0.5f*(Xk1.y - Xc1.y);
        // twiddle i*(ca,sa) = (-sa, ca)
        const float Or1 = -sa*Tr1 - ca*Ti1;
        const float Oi1 = -sa*Ti1 + ca*Tr1;
        const float2 Z1 = make_float2(Er1 - Oi1, Ei1 + Or1);
        const float drr = Z0.x - Z1.x, dii = Z0.y - Z1.y;
        float4 outv;
        outv.x = Z0.x + Z1.x;
        outv.y = Z0.y + Z1.y;
        outv.z = cw0*drr - sw0*dii;
        outv.w = cw0*dii + sw0*drr;
        *reinterpret_cast<float4*>(&bufA[2*tid]) = outv;
    }
    __syncthreads();

    // ---------------- Merged FFT stages: (m,2m) for m = 2, 8, 32, 128 ----------------
    // Thread (c,eps) computes level-2 butterfly at u = 2*jm1 + eps*m + r from
    // X[c], X[c+256], X[c+512], X[c+768]; writes p = 4*jm1 + eps*m + r and p+2m.
    // Level-1: eps=0 slot = sum, eps=1 slot = w1*diff (second pair uses i*w1);
    // level-2 twiddle W = w1^2.
    float2* Xb = bufA;
    float2* Yb = bufB;
    #pragma unroll
    for (int mi = 0; mi < 4; ++mi) {
        const int m   = 2 << (2*mi);
        const int jm1 = c & ~(m - 1);
        const int r   = c & (m - 1);
        const float c1v = w1c[mi], s1 = w1s[mi];
        const float2 x0 = Xb[c];
        const float2 x1 = Xb[c + 256];
        const float2 x2 = Xb[c + 512];
        const float2 x3 = Xb[c + 768];
        const float2 s02 = make_float2(x0.x + x2.x, x0.y + x2.y);
        const float2 d02 = make_float2(x0.x - x2.x, x0.y - x2.y);
        const float2 s13 = make_float2(x1.x + x3.x, x1.y + x3.y);
        const float2 d13 = make_float2(x1.x - x3.x, x1.y - x3.y);
        const float2 wd02 = make_float2(c1v*d02.x - s1*d02.y, c1v*d02.y + s1*d02.x);
        const float2 wd13 = make_float2(-s1*d13.x - c1v*d13.y, c1v*d13.x - s1*d13.y);
        const float2 Yu = eps ? wd02 : s02;
        const float2 Yv = eps ? wd13 : s13;
        const float Wc = c1v*c1v - s1*s1;     // W = w1^2
        const float Ws = 2.f*c1v*s1;
        const float2 Zp = make_float2(Yu.x + Yv.x, Yu.y + Yv.y);
        const float2 Zd = make_float2(Yu.x - Yv.x, Yu.y - Yv.y);
        const int p = 4*jm1 + (eps ? m : 0) + r;
        Yb[p]       = Zp;
        Yb[p + 2*m] = make_float2(Wc*Zd.x - Ws*Zd.y, Wc*Zd.y + Ws*Zd.x);
        __syncthreads();
        float2* t = Xb; Xb = Yb; Yb = t;
    }

    // ---------------- Final stage m=512 (twiddle-free) fused with store ----------------
    {
        const float sc = 1.0f/1024.0f;
        float2* op2 = (float2*)(out + (size_t)h * LFULL);
        const float2 a0 = Xb[tid];
        const float2 a1 = Xb[tid + 512];
        op2[tid]       = make_float2((a0.x + a1.x)*sc, (a0.y + a1.y)*sc);
        op2[tid + 512] = make_float2((a0.x - a1.x)*sc, (a0.y - a1.y)*sc);
    }
}

extern "C" void kernel_launch(void* const* d_in, const int* in_sizes, int n_in,
                              void* d_out, int out_size, void* d_ws, size_t ws_size,
                              hipStream_t stream) {
    const float* w_ri   = (const float*)d_in[0];
    const float* P_ri   = (const float*)d_in[1];
    const float* B_ri   = (const float*)d_in[2];
    const float* C_ri   = (const float*)d_in[3];
    const float* log_dt = (const float*)d_in[4];
    float* out = (float*)d_out;
    const int Hn = in_sizes[4];   // 256 heads
    hippo_ssk<<<dim3(Hn), dim3(512), 0, stream>>>(w_ri, P_ri, B_ri, C_ri, log_dt, out);
}